// Round 1
// baseline (73805.359 us; speedup 1.0000x reference)
//
#include <hip/hip_runtime.h>
#include <hip/hip_cooperative_groups.h>

namespace cg = cooperative_groups;

#define NTHREADS 512
#define BT 16   // batch tile per workgroup

constexpr int Bsz = 256, Tst = 128, HID = 1440;
constexpr int ORN = 384, PN = 112, LN = 64, KC = 864, MB = 16, OBS = 64;

struct Params {
  const float *obs, *h, *in_orn_w, *in_orn_b, *W_oto, *W_lto, *W_otp, *W_ltp, *W_ptp,
              *W_otl, *W_ptl, *W_ltl, *W_ktk, *W_mtk, *W_ptk, *W_ktm,
              *b_orn, *b_pn, *b_ln, *b_kc, *b_mbon, *readout_w, *readout_b;
  float *orn0, *orn1, *pn0, *pn1, *ln0, *ln1, *kc0, *kc1, *mbon, *y, *h2;
  int *bar;
};

// ======================= coherent (device-scope, L2-bypass) access =======================
// State buffers are the only cross-XCD data. All accesses to them use sc1-scoped
// (agent) relaxed atomics -> always served at the coherence point (LLC), never cached
// in the per-XCD L2. This lets us drop ALL fences (buffer_inv/buffer_wbl2) from the
// barrier, so the read-only weights stay L2-resident across all 512 steps.
__device__ __forceinline__ float2 ld2cg(const float* p) {
  unsigned long long u = __hip_atomic_load((const unsigned long long*)p,
      __ATOMIC_RELAXED, __HIP_MEMORY_SCOPE_AGENT);
  union { unsigned long long u; float2 f; } c; c.u = u; return c.f;
}
__device__ __forceinline__ float ld1cg(const float* p) {
  unsigned int u = __hip_atomic_load((const unsigned int*)p,
      __ATOMIC_RELAXED, __HIP_MEMORY_SCOPE_AGENT);
  return __uint_as_float(u);
}
__device__ __forceinline__ void st1cg(float* p, float v) {
  __hip_atomic_store((unsigned int*)p, __float_as_uint(v),
      __ATOMIC_RELAXED, __HIP_MEMORY_SCOPE_AGENT);
}
__device__ __forceinline__ void st2cg(float* p, float a, float b) {
  union { unsigned long long u; float2 f; } c; c.f = make_float2(a, b);
  __hip_atomic_store((unsigned long long*)p, c.u,
      __ATOMIC_RELAXED, __HIP_MEMORY_SCOPE_AGENT);
}

// ---- ILP-4 dot over LDS/cached pointers (unchanged) ----
template <int K>
__device__ __forceinline__ float dot4(const float* __restrict__ w, const float* __restrict__ a) {
  const float4* w4 = (const float4*)w;
  const float4* a4 = (const float4*)a;
  float x0 = 0.f, x1 = 0.f, x2 = 0.f, x3 = 0.f;
#pragma unroll 4
  for (int i = 0; i < K / 4; ++i) {
    float4 wv = w4[i], av = a4[i];
    x0 = fmaf(wv.x, av.x, x0); x1 = fmaf(wv.y, av.y, x1);
    x2 = fmaf(wv.z, av.z, x2); x3 = fmaf(wv.w, av.w, x3);
  }
  return (x0 + x1) + (x2 + x3);
}

// ---- dot: cached weights x coherent (sc1) activations; fully unrolled so the
//      independent sc-loads pipeline (waits inserted only at first use) ----
template <int K>
__device__ __forceinline__ float dotg(const float* __restrict__ w, const float* a) {
  const float4* w4 = (const float4*)w;
  float x0 = 0.f, x1 = 0.f, x2 = 0.f, x3 = 0.f;
#pragma unroll
  for (int i = 0; i < K / 4; ++i) {
    float4 wv = w4[i];
    float2 a0 = ld2cg(a + 4 * i);
    float2 a1 = ld2cg(a + 4 * i + 2);
    x0 = fmaf(wv.x, a0.x, x0); x1 = fmaf(wv.y, a0.y, x1);
    x2 = fmaf(wv.z, a1.x, x2); x3 = fmaf(wv.w, a1.y, x3);
  }
  return (x0 + x1) + (x2 + x3);
}

// ---- dual-output dot from LDS (unchanged) ----
template <int K>
__device__ __forceinline__ void ddot(const float* __restrict__ w0, const float* __restrict__ w1,
                                     const float* __restrict__ a, float& r0, float& r1) {
  const float4* W0 = (const float4*)w0;
  const float4* W1 = (const float4*)w1;
  const float4* A  = (const float4*)a;
  float x0=0,x1=0,x2=0,x3=0, y0=0,y1=0,y2=0,y3=0;
#pragma unroll 4
  for (int i = 0; i < K / 4; ++i) {
    float4 av = A[i], u = W0[i], v = W1[i];
    x0 = fmaf(u.x, av.x, x0); x1 = fmaf(u.y, av.y, x1);
    x2 = fmaf(u.z, av.z, x2); x3 = fmaf(u.w, av.w, x3);
    y0 = fmaf(v.x, av.x, y0); y1 = fmaf(v.y, av.y, y1);
    y2 = fmaf(v.z, av.z, y2); y3 = fmaf(v.w, av.w, y3);
  }
  r0 += (x0 + x1) + (x2 + x3);
  r1 += (y0 + y1) + (y2 + y3);
}

// ---- stage a [BT x WIDTH] state segment into LDS via coherent 8B loads.
//      Fixed trip count + load-all-then-write-all (static reg indices) so all
//      NIT sc-loads are outstanding before the first ds_write waits. ----
template <int WIDTH>
__device__ __forceinline__ void stage_seg(float* dst, int stride, int off,
                                          const float* g, int b0, int tid) {
  constexpr int W2  = WIDTH / 2;
  constexpr int TOT = BT * W2;
  constexpr int NIT = (TOT + NTHREADS - 1) / NTHREADS;
  const float* base = g + (size_t)b0 * WIDTH;
  float2 v[NIT];
#pragma unroll
  for (int j = 0; j < NIT; ++j) {
    int idx = tid + j * NTHREADS; if (idx >= TOT) idx = TOT - 1;
    int b = idx / W2, k = idx - b * W2;
    v[j] = ld2cg(base + (size_t)b * WIDTH + 2 * k);
  }
#pragma unroll
  for (int j = 0; j < NIT; ++j) {
    int idx = tid + j * NTHREADS;
    if (idx < TOT) {
      int b = idx / W2, k = idx - b * W2;
      *(float2*)(dst + b * stride + off + 2 * k) = v[j];
    }
  }
}

// ---- 16-WG barrier, FENCE-FREE: all atomics relaxed (no buffer_inv / buffer_wbl2).
//      __syncthreads drains each wave's vmcnt (sc1 stores acked at LLC) before tid0
//      signals; explicit vmcnt(0) orders the cnt reset before the gen bump. ----
__device__ __forceinline__ void bar_sync(int* cnt, int* gen, int& lg, int tid) {
  __syncthreads();
  if (tid == 0) {
    int target = ++lg;
    int old = __hip_atomic_fetch_add(cnt, 1, __ATOMIC_RELAXED, __HIP_MEMORY_SCOPE_AGENT);
    if (old == 15) {
      __hip_atomic_store(cnt, 0, __ATOMIC_RELAXED, __HIP_MEMORY_SCOPE_AGENT);
      asm volatile("s_waitcnt vmcnt(0)" ::: "memory");  // cnt reset durable before release
      __hip_atomic_fetch_add(gen, 1, __ATOMIC_RELAXED, __HIP_MEMORY_SCOPE_AGENT);
    } else {
      while (__hip_atomic_load(gen, __ATOMIC_RELAXED, __HIP_MEMORY_SCOPE_AGENT) < target)
        __builtin_amdgcn_s_sleep(1);
    }
  }
  __syncthreads();
}

__global__ void __launch_bounds__(NTHREADS, 1)
conn_kernel(Params P) {
  cg::grid_group grid = cg::this_grid();
  // strides 452/564/996: b*stride mod 32 spans >=8 banks -> <=2-way alias (free).
  // 16*996*4 + 16*24*4 = 65280 B <= 64 KiB static LDS limit.
  __shared__ float act[BT * 996];
  __shared__ float xs[BT * 24];
  const int tid = threadIdx.x;
  const int wg = blockIdx.x, bg = wg >> 4, ng = wg & 15, b0 = bg * BT;
  // ng = wg & 15 keeps only 2 distinct ng weight slices per XCD (~572 KB) -> L2-resident.
  int* cnt = P.bar + bg * 64;
  int* gen = P.bar + bg * 64 + 16;
  int lg = 0;

  // ---- init: scatter h into parity-1 state buffers (coherent stores); init barrier ----
  if (ng == 0) {
    if (tid == 0) {
      __hip_atomic_store(cnt, 0, __ATOMIC_RELAXED, __HIP_MEMORY_SCOPE_AGENT);
      __hip_atomic_store(gen, 0, __ATOMIC_RELAXED, __HIP_MEMORY_SCOPE_AGENT);
    }
    for (int idx = tid; idx < BT * HID; idx += NTHREADS) {
      int b = idx / HID, pos = idx - b * HID, gb = b0 + b;
      float v = P.h[(size_t)gb * HID + pos];
      if      (pos < 384)  st1cg(&P.orn1[(size_t)gb * ORN + pos], v);
      else if (pos < 496)  st1cg(&P.pn1[gb * PN + (pos - 384)], v);
      else if (pos < 560)  st1cg(&P.ln1[gb * LN + (pos - 496)], v);
      else if (pos < 1424) st1cg(&P.kc1[(size_t)gb * KC + (pos - 560)], v);
      else                 st1cg(&P.mbon[gb * MB + (pos - 1424)], v);
    }
  }
  grid.sync();  // once: publishes init + barrier zeros

  for (int s = 0; s < Tst * 4; ++s) {
    const int t = s >> 2, i = s & 3, p = s & 1;
    float* ornN = p ? P.orn1 : P.orn0;  const float* ornO = p ? P.orn0 : P.orn1;
    float* pnN  = p ? P.pn1  : P.pn0;   const float* pnO  = p ? P.pn0  : P.pn1;
    float* lnN  = p ? P.ln1  : P.ln0;   const float* lnO  = p ? P.ln0  : P.ln1;
    float* kcN  = p ? P.kc1  : P.kc0;   const float* kcO  = p ? P.kc0  : P.kc1;

    // ================= Stage A: orn_i (0-191) + mbon_{s-1} (192-319) =================
    stage_seg<ORN>(act, 452, 0,   ornO, b0, tid);
    stage_seg<LN >(act, 452, 384, lnO,  b0, tid);
    if (i == 0 && tid >= 320) {  // x_t slice, once per timestep, overlaps staging
      for (int o = tid - 320; o < BT * 24; o += 192) {
        int b = o / 24, jl = o - b * 24, j = ng * 24 + jl;
        xs[b * 24 + jl] = P.in_orn_b[j]
          + dot4<OBS>(P.in_orn_w + (size_t)j * OBS,
                      P.obs + ((size_t)(b0 + b) * Tst + t) * OBS);
      }
    }
    __syncthreads();
    if (tid < 192) {
      int b = tid & 15, jp = tid >> 4;
      int j0 = ng * 24 + jp * 2, j1 = j0 + 1;
      float r0 = xs[b * 24 + jp * 2]     + P.b_orn[j0];
      float r1 = xs[b * 24 + jp * 2 + 1] + P.b_orn[j1];
      ddot<ORN>(P.W_oto + (size_t)j0 * ORN, P.W_oto + (size_t)j1 * ORN, act + b * 452, r0, r1);
      ddot<LN> (P.W_lto + (size_t)j0 * LN,  P.W_lto + (size_t)j1 * LN,  act + b * 452 + 384, r0, r1);
      st2cg(&ornN[(size_t)(b0 + b) * ORN + j0], tanhf(r0), tanhf(r1));
    } else if (tid < 320 && s > 0) {  // mbon: coherent reads of kcO (no reuse)
      int idx = tid - 192, b = idx >> 3, ks = idx & 7;
      float part = dotg<108>(P.W_ktm + (size_t)ng * KC + ks * 108,
                             kcO + (size_t)(b0 + b) * KC + ks * 108);
      part += __shfl_xor(part, 1);
      part += __shfl_xor(part, 2);
      part += __shfl_xor(part, 4);
      if (ks == 0)
        st1cg(&P.mbon[(b0 + b) * MB + ng], tanhf(part + P.b_mbon[ng]));
    }
    bar_sync(cnt, gen, lg, tid);

    // ================= Stage B: pn_i (LDS-staged) + y_{t-1} =================
    stage_seg<ORN>(act, 564, 0,   ornN, b0, tid);
    stage_seg<LN >(act, 564, 384, lnO,  b0, tid);
    stage_seg<PN >(act, 564, 448, pnO,  b0, tid);
    __syncthreads();
    if (tid < 112) {
      int b = tid & 15, jl = tid >> 4, j = ng * 7 + jl;
      const float* A = act + b * 564;
      float acc = P.b_pn[j]
        + dot4<ORN>(P.W_otp + (size_t)j * ORN, A)
        + dot4<LN> (P.W_ltp + (size_t)j * LN,  A + 384)
        + dot4<PN> (P.W_ptp + (size_t)j * PN,  A + 448);
      st1cg(&pnN[(size_t)(b0 + b) * PN + j], tanhf(acc));
    } else if (i == 0 && s > 0) {  // y_{t-1}: rank-16 readout from mbon
      for (int o = tid - 112; o < BT * 90; o += 400) {
        int b = o / 90, jl = o - b * 90, j = ng * 90 + jl;
        float acc = P.readout_b[j]
          + dotg<MB>(P.readout_w + (size_t)j * MB, P.mbon + (size_t)(b0 + b) * MB);
        P.y[((size_t)(b0 + b) * Tst + (t - 1)) * HID + j] = acc;
      }
    }
    bar_sync(cnt, gen, lg, tid);

    // ================= Stage C: kc_i (0-431, LDS) + ln_i (448-511) =================
    stage_seg<KC>(act, 996, 0,   kcO,    b0, tid);
    stage_seg<PN>(act, 996, 864, pnN,    b0, tid);
    stage_seg<MB>(act, 996, 976, P.mbon, b0, tid);
    __syncthreads();
    if (tid < 432) {
      int b = tid & 15, jp = tid >> 4;
      int j0 = ng * 54 + jp * 2, j1 = j0 + 1;
      float r0 = P.b_kc[j0], r1 = P.b_kc[j1];
      ddot<KC>(P.W_ktk + (size_t)j0 * KC, P.W_ktk + (size_t)j1 * KC, act + b * 996, r0, r1);
      ddot<PN>(P.W_ptk + (size_t)j0 * PN, P.W_ptk + (size_t)j1 * PN, act + b * 996 + 864, r0, r1);
      ddot<MB>(P.W_mtk + (size_t)j0 * MB, P.W_mtk + (size_t)j1 * MB, act + b * 996 + 976, r0, r1);
      st2cg(&kcN[(size_t)(b0 + b) * KC + j0], tanhf(r0), tanhf(r1));
    } else if (tid >= 448) {
      int b = (tid - 448) & 15, jl = (tid - 448) >> 4, j = ng * 4 + jl;
      float acc = P.b_ln[j]
        + dotg<ORN>(P.W_otl + (size_t)j * ORN, ornN + (size_t)(b0 + b) * ORN)
        + dot4<PN> (P.W_ptl + (size_t)j * PN,  act + b * 996 + 864)   // pn from staged LDS
        + dotg<LN> (P.W_ltl + (size_t)j * LN,  lnO + (size_t)(b0 + b) * LN);
      st1cg(&lnN[(size_t)(b0 + b) * LN + j], tanhf(acc));
    }
    bar_sync(cnt, gen, lg, tid);
  }

  // ================= tail: mbon_{511}, y_{127}, h2 =================
  if (tid >= 192 && tid < 320) {
    int idx = tid - 192, b = idx >> 3, ks = idx & 7;
    float part = dotg<108>(P.W_ktm + (size_t)ng * KC + ks * 108,
                           P.kc1 + (size_t)(b0 + b) * KC + ks * 108);
    part += __shfl_xor(part, 1);
    part += __shfl_xor(part, 2);
    part += __shfl_xor(part, 4);
    if (ks == 0)
      st1cg(&P.mbon[(b0 + b) * MB + ng], tanhf(part + P.b_mbon[ng]));
  }
  bar_sync(cnt, gen, lg, tid);
  for (int o = tid; o < BT * 90; o += NTHREADS) {
    int b = o / 90, jl = o - b * 90, j = ng * 90 + jl;
    float acc = P.readout_b[j]
      + dotg<MB>(P.readout_w + (size_t)j * MB, P.mbon + (size_t)(b0 + b) * MB);
    P.y[((size_t)(b0 + b) * Tst + (Tst - 1)) * HID + j] = acc;
  }
  for (int idx = tid; idx < BT * 90; idx += NTHREADS) {
    int b = idx / 90, pos = idx - b * 90, gb = b0 + b;
    float v; int hp;
    if      (pos < 24) { v = ld1cg(&P.orn1[(size_t)gb * ORN + ng * 24 + pos]); hp = ng * 24 + pos; }
    else if (pos < 31) { int l = pos - 24; v = ld1cg(&P.pn1[gb * PN + ng * 7 + l]); hp = 384 + ng * 7 + l; }
    else if (pos < 35) { int l = pos - 31; v = ld1cg(&P.ln1[gb * LN + ng * 4 + l]); hp = 496 + ng * 4 + l; }
    else if (pos < 89) { int l = pos - 35; v = ld1cg(&P.kc1[(size_t)gb * KC + ng * 54 + l]); hp = 560 + ng * 54 + l; }
    else               { v = ld1cg(&P.mbon[gb * MB + ng]); hp = 1424 + ng; }
    P.h2[(size_t)gb * HID + hp] = v;
  }
}

extern "C" void kernel_launch(void* const* d_in, const int* in_sizes, int n_in,
                              void* d_out, int out_size, void* d_ws, size_t ws_size,
                              hipStream_t stream) {
  Params P;
  P.obs       = (const float*)d_in[0];
  P.h         = (const float*)d_in[1];
  P.in_orn_w  = (const float*)d_in[2];
  P.in_orn_b  = (const float*)d_in[3];
  P.W_oto     = (const float*)d_in[4];
  P.W_lto     = (const float*)d_in[5];
  P.W_otp     = (const float*)d_in[6];
  P.W_ltp     = (const float*)d_in[7];
  P.W_ptp     = (const float*)d_in[8];
  P.W_otl     = (const float*)d_in[9];
  P.W_ptl     = (const float*)d_in[10];
  P.W_ltl     = (const float*)d_in[11];
  P.W_ktk     = (const float*)d_in[12];
  P.W_mtk     = (const float*)d_in[13];
  P.W_ptk     = (const float*)d_in[14];
  P.W_ktm     = (const float*)d_in[15];
  P.b_orn     = (const float*)d_in[16];
  P.b_pn      = (const float*)d_in[17];
  P.b_ln      = (const float*)d_in[18];
  P.b_kc      = (const float*)d_in[19];
  P.b_mbon    = (const float*)d_in[20];
  P.readout_w = (const float*)d_in[21];
  P.readout_b = (const float*)d_in[22];

  float* ws = (float*)d_ws;
  size_t off = 0;
  P.orn0 = ws + off; off += (size_t)Bsz * ORN;
  P.orn1 = ws + off; off += (size_t)Bsz * ORN;
  P.pn0  = ws + off; off += (size_t)Bsz * PN;
  P.pn1  = ws + off; off += (size_t)Bsz * PN;
  P.ln0  = ws + off; off += (size_t)Bsz * LN;
  P.ln1  = ws + off; off += (size_t)Bsz * LN;
  P.kc0  = ws + off; off += (size_t)Bsz * KC;
  P.kc1  = ws + off; off += (size_t)Bsz * KC;
  P.mbon = ws + off; off += (size_t)Bsz * MB;
  P.bar  = (int*)(ws + off); off += 16 * 64;  // 16 batch groups x 64 ints (cnt/gen cachelines)

  P.y  = (float*)d_out;
  P.h2 = (float*)d_out + (size_t)Bsz * Tst * HID;

  void* args[] = { &P };
  hipLaunchCooperativeKernel((void*)conn_kernel, dim3(256), dim3(NTHREADS), args, 0, stream);
}

// Round 2
// 27721.793 us; speedup vs baseline: 2.6624x; 2.6624x over previous
//
#include <hip/hip_runtime.h>
#include <hip/hip_cooperative_groups.h>

namespace cg = cooperative_groups;

#define NTHREADS 512
#define BT 16   // batch tile per workgroup group

constexpr int Bsz = 256, Tst = 128, HID = 1440;
constexpr int ORN = 384, PN = 112, LN = 64, KC = 864, MB = 16, OBS = 64;

struct Params {
  const float *obs, *h, *in_orn_w, *in_orn_b, *W_oto, *W_lto, *W_otp, *W_ltp, *W_ptp,
              *W_otl, *W_ptl, *W_ltl, *W_ktk, *W_mtk, *W_ptk, *W_ktm,
              *b_orn, *b_pn, *b_ln, *b_kc, *b_mbon, *readout_w, *readout_b;
  float *orn0, *orn1, *pn0, *pn1, *ln0, *ln1, *kc0, *kc1, *mbon, *y, *h2;
  int *bar;
};

// ---- ILP-4 dot (plain cached loads: state is XCD-L2-resident by construction) ----
template <int K>
__device__ __forceinline__ float dot4(const float* __restrict__ w, const float* __restrict__ a) {
  const float4* w4 = (const float4*)w;
  const float4* a4 = (const float4*)a;
  float x0 = 0.f, x1 = 0.f, x2 = 0.f, x3 = 0.f;
#pragma unroll 4
  for (int i = 0; i < K / 4; ++i) {
    float4 wv = w4[i], av = a4[i];
    x0 = fmaf(wv.x, av.x, x0); x1 = fmaf(wv.y, av.y, x1);
    x2 = fmaf(wv.z, av.z, x2); x3 = fmaf(wv.w, av.w, x3);
  }
  return (x0 + x1) + (x2 + x3);
}

// ---- dual-output dot from LDS ----
template <int K>
__device__ __forceinline__ void ddot(const float* __restrict__ w0, const float* __restrict__ w1,
                                     const float* __restrict__ a, float& r0, float& r1) {
  const float4* W0 = (const float4*)w0;
  const float4* W1 = (const float4*)w1;
  const float4* A  = (const float4*)a;
  float x0=0,x1=0,x2=0,x3=0, y0=0,y1=0,y2=0,y3=0;
#pragma unroll 4
  for (int i = 0; i < K / 4; ++i) {
    float4 av = A[i], u = W0[i], v = W1[i];
    x0 = fmaf(u.x, av.x, x0); x1 = fmaf(u.y, av.y, x1);
    x2 = fmaf(u.z, av.z, x2); x3 = fmaf(u.w, av.w, x3);
    y0 = fmaf(v.x, av.x, y0); y1 = fmaf(v.y, av.y, y1);
    y2 = fmaf(v.z, av.z, y2); y3 = fmaf(v.w, av.w, y3);
  }
  r0 += (x0 + x1) + (x2 + x3);
  r1 += (y0 + y1) + (y2 + y3);
}

// ---- stage a [BT x width] state segment into LDS (plain cached float4 loads) ----
__device__ __forceinline__ void load_seg(float* dst, int stride, int off,
                                         const float* g, int width, int b0, int tid) {
  int w4 = width >> 2;
  const float4* g4 = (const float4*)(g + (size_t)b0 * width);
  for (int idx = tid; idx < BT * w4; idx += NTHREADS) {
    int b = idx / w4, k = idx - b * w4;
    *(float4*)(dst + b * stride + off + 4 * k) = g4[(size_t)b * w4 + k];
  }
}

// ---- 16-WG barrier. Flags: relaxed agent atomics (LLC). Data: stays in the XCD L2
//      (all 16 WGs of a bg are co-located on one XCD: bg = wg & 15 under the
//      round-robin blockIdx->XCD mapping, stride 16 == 0 mod 8).
//      Release: vmcnt(0) (stores write through L1 into L2). Acquire: L1-ONLY
//      invalidate (buffer_inv sc0) -- the L2 (weights + state) is NEVER flushed. ----
__device__ __forceinline__ void bar_sync(int* cnt, int* gen, int& lg, int tid) {
  __syncthreads();   // compiler drains each wave's vmcnt before s_barrier
  if (tid == 0) {
    int target = ++lg;
    asm volatile("s_waitcnt vmcnt(0)" ::: "memory");   // our stores visible in L2
    int old = __hip_atomic_fetch_add(cnt, 1, __ATOMIC_RELAXED, __HIP_MEMORY_SCOPE_AGENT);
    if (old == 15) {
      __hip_atomic_store(cnt, 0, __ATOMIC_RELAXED, __HIP_MEMORY_SCOPE_AGENT);
      asm volatile("s_waitcnt vmcnt(0)" ::: "memory");
      __hip_atomic_fetch_add(gen, 1, __ATOMIC_RELAXED, __HIP_MEMORY_SCOPE_AGENT);
    } else {
      while (__hip_atomic_load(gen, __ATOMIC_RELAXED, __HIP_MEMORY_SCOPE_AGENT) < target)
        __builtin_amdgcn_s_sleep(1);
    }
    asm volatile("buffer_inv sc0\n\ts_waitcnt vmcnt(0)" ::: "memory");  // L1-only inv
  }
  __syncthreads();
}

__global__ void __launch_bounds__(NTHREADS, 1)
conn_kernel(Params P) {
  cg::grid_group grid = cg::this_grid();
  // 16*996*4 + 16*24*4 = 65280 B <= 64 KiB static LDS limit.
  __shared__ float act[BT * 996];
  __shared__ float xs[BT * 24];
  const int tid = threadIdx.x;
  const int wg = blockIdx.x;
  // bg = wg & 15: group members {bg, bg+16, ..., bg+240} all map to XCD (bg&7)
  // under round-robin dispatch -> all state sharing is same-L2 (coherence point).
  const int bg = wg & 15, ng = wg >> 4, b0 = bg * BT;
  int* cnt = P.bar + bg * 64;
  int* gen = P.bar + bg * 64 + 16;
  int lg = 0;

  // ---- init: scatter h into parity-1 state buffers; init this bg's barrier ----
  if (ng == 0) {
    if (tid == 0) { *cnt = 0; *gen = 0; }
    for (int idx = tid; idx < BT * HID; idx += NTHREADS) {
      int b = idx / HID, pos = idx - b * HID, gb = b0 + b;
      float v = P.h[(size_t)gb * HID + pos];
      if      (pos < 384)  P.orn1[(size_t)gb * ORN + pos] = v;
      else if (pos < 496)  P.pn1[gb * PN + (pos - 384)] = v;
      else if (pos < 560)  P.ln1[gb * LN + (pos - 496)] = v;
      else if (pos < 1424) P.kc1[(size_t)gb * KC + (pos - 560)] = v;
      else                 P.mbon[gb * MB + (pos - 1424)] = v;
    }
  }
  grid.sync();  // once: publishes init + barrier zeros

  for (int s = 0; s < Tst * 4; ++s) {
    const int t = s >> 2, i = s & 3, p = s & 1;
    float* ornN = p ? P.orn1 : P.orn0;  const float* ornO = p ? P.orn0 : P.orn1;
    float* pnN  = p ? P.pn1  : P.pn0;   const float* pnO  = p ? P.pn0  : P.pn1;
    float* lnN  = p ? P.ln1  : P.ln0;   const float* lnO  = p ? P.ln0  : P.ln1;
    float* kcN  = p ? P.kc1  : P.kc0;   const float* kcO  = p ? P.kc0  : P.kc1;

    // ========== Stage A: orn_i, split-K x2 (tid 0-383) + x_t (384-511, i==0) ==========
    load_seg(act, 452, 0,   ornO, ORN, b0, tid);
    load_seg(act, 452, 384, lnO,  LN,  b0, tid);
    if (i == 0 && tid >= 384) {  // x_t slice, once per timestep, overlaps staging
      for (int o = tid - 384; o < BT * 24; o += 128) {
        int b = o / 24, jl = o - b * 24, j = ng * 24 + jl;
        xs[b * 24 + jl] = P.in_orn_b[j]
          + dot4<OBS>(P.in_orn_w + (size_t)j * OBS,
                      P.obs + ((size_t)(b0 + b) * Tst + t) * OBS);
      }
    }
    __syncthreads();
    if (tid < 384) {
      int b = tid & 15, half = (tid >> 4) & 1, jp = tid >> 5;   // partner = tid^16 (same wave)
      int j0 = ng * 24 + jp * 2, j1 = j0 + 1;
      float r0 = 0.f, r1 = 0.f;
      if (half == 0) { r0 = xs[b * 24 + jp * 2] + P.b_orn[j0]; r1 = xs[b * 24 + jp * 2 + 1] + P.b_orn[j1]; }
      ddot<192>(P.W_oto + (size_t)j0 * ORN + half * 192, P.W_oto + (size_t)j1 * ORN + half * 192,
                act + b * 452 + half * 192, r0, r1);
      ddot<32> (P.W_lto + (size_t)j0 * LN + half * 32,  P.W_lto + (size_t)j1 * LN + half * 32,
                act + b * 452 + 384 + half * 32, r0, r1);
      r0 += __shfl_xor(r0, 16);
      r1 += __shfl_xor(r1, 16);
      if (half == 0)
        *(float2*)&ornN[(size_t)(b0 + b) * ORN + j0] = make_float2(tanhf(r0), tanhf(r1));
    }
    bar_sync(cnt, gen, lg, tid);

    // ========== Stage B: pn_i split-K x4 (tid 0-447) + mbon_{s-1} x4 (448-511) ==========
    load_seg(act, 564, 0,   ornN, ORN, b0, tid);
    load_seg(act, 564, 384, lnO,  LN,  b0, tid);
    load_seg(act, 564, 448, pnO,  PN,  b0, tid);
    __syncthreads();
    if (tid < 448) {
      int b = tid & 15, q = (tid >> 4) & 3, jl = tid >> 6;  // partners tid^16, tid^32 (same wave)
      int j = ng * 7 + jl;
      const float* A = act + b * 564;
      float acc = 0.f;
      if      (q == 0) acc = P.b_pn[j] + dot4<192>(P.W_otp + (size_t)j * ORN,       A);
      else if (q == 1) acc = dot4<192>(P.W_otp + (size_t)j * ORN + 192, A + 192);
      else if (q == 2) acc = dot4<64>(P.W_ltp + (size_t)j * LN, A + 384)
                           + dot4<48>(P.W_ptp + (size_t)j * PN, A + 448);
      else             acc = dot4<64>(P.W_ptp + (size_t)j * PN + 48, A + 496);
      acc += __shfl_xor(acc, 16);
      acc += __shfl_xor(acc, 32);
      if (q == 0)
        pnN[(size_t)(b0 + b) * PN + j] = tanhf(acc);
    } else if (s > 0) {  // mbon_{s-1}: 64 threads, 4-way K-split of 864
      int idx = tid - 448, b = idx >> 2, ks = idx & 3;
      float part = dot4<216>(P.W_ktm + (size_t)ng * KC + ks * 216,
                             kcO + (size_t)(b0 + b) * KC + ks * 216);
      part += __shfl_xor(part, 1);
      part += __shfl_xor(part, 2);
      if (ks == 0)
        P.mbon[(b0 + b) * MB + ng] = tanhf(part + P.b_mbon[ng]);
    }
    bar_sync(cnt, gen, lg, tid);

    // ========== Stage C: kc_i (0-431, LDS) + ln_i & y_{t-1} (448-511) ==========
    load_seg(act, 996, 0,   kcO,    KC, b0, tid);
    load_seg(act, 996, 864, pnN,    PN, b0, tid);
    load_seg(act, 996, 976, P.mbon, MB, b0, tid);
    __syncthreads();
    if (tid < 432) {
      int b = tid & 15, jp = tid >> 4;
      int j0 = ng * 54 + jp * 2, j1 = j0 + 1;
      float r0 = P.b_kc[j0], r1 = P.b_kc[j1];
      ddot<KC>(P.W_ktk + (size_t)j0 * KC, P.W_ktk + (size_t)j1 * KC, act + b * 996, r0, r1);
      ddot<PN>(P.W_ptk + (size_t)j0 * PN, P.W_ptk + (size_t)j1 * PN, act + b * 996 + 864, r0, r1);
      ddot<MB>(P.W_mtk + (size_t)j0 * MB, P.W_mtk + (size_t)j1 * MB, act + b * 996 + 976, r0, r1);
      *(float2*)&kcN[(size_t)(b0 + b) * KC + j0] = make_float2(tanhf(r0), tanhf(r1));
    } else if (tid >= 448) {
      int b = (tid - 448) & 15, jl = (tid - 448) >> 4, j = ng * 4 + jl;
      const float* ornRow = ornN + (size_t)(b0 + b) * ORN;
      const float* lnRow  = lnO  + (size_t)(b0 + b) * LN;
      float acc = P.b_ln[j]
        + dot4<ORN>(P.W_otl + (size_t)j * ORN, ornRow)
        + dot4<PN> (P.W_ptl + (size_t)j * PN,  act + b * 996 + 864)   // pn from staged LDS
        + dot4<LN> (P.W_ltl + (size_t)j * LN,  lnRow);
      lnN[(size_t)(b0 + b) * LN + j] = tanhf(acc);
      if (i == 0 && s > 0) {  // y_{t-1}: rank-16 readout from mbon_{s-1}
        for (int o = tid - 448; o < BT * 90; o += 64) {
          int b2 = o / 90, jl2 = o - b2 * 90, j2 = ng * 90 + jl2;
          float yv = P.readout_b[j2]
            + dot4<MB>(P.readout_w + (size_t)j2 * MB, P.mbon + (size_t)(b0 + b2) * MB);
          P.y[((size_t)(b0 + b2) * Tst + (t - 1)) * HID + j2] = yv;
        }
      }
    }
    bar_sync(cnt, gen, lg, tid);
  }

  // ================= tail: mbon_{511}, y_{127}, h2 =================
  if (tid >= 192 && tid < 320) {
    int idx = tid - 192, b = idx >> 3, ks = idx & 7;
    float part = dot4<108>(P.W_ktm + (size_t)ng * KC + ks * 108,
                           P.kc1 + (size_t)(b0 + b) * KC + ks * 108);
    part += __shfl_xor(part, 1);
    part += __shfl_xor(part, 2);
    part += __shfl_xor(part, 4);
    if (ks == 0)
      P.mbon[(b0 + b) * MB + ng] = tanhf(part + P.b_mbon[ng]);
  }
  bar_sync(cnt, gen, lg, tid);
  for (int o = tid; o < BT * 90; o += NTHREADS) {
    int b = o / 90, jl = o - b * 90, j = ng * 90 + jl;
    float acc = P.readout_b[j]
      + dot4<MB>(P.readout_w + (size_t)j * MB, P.mbon + (size_t)(b0 + b) * MB);
    P.y[((size_t)(b0 + b) * Tst + (Tst - 1)) * HID + j] = acc;
  }
  for (int idx = tid; idx < BT * 90; idx += NTHREADS) {
    int b = idx / 90, pos = idx - b * 90, gb = b0 + b;
    float v; int hp;
    if      (pos < 24) { v = P.orn1[(size_t)gb * ORN + ng * 24 + pos]; hp = ng * 24 + pos; }
    else if (pos < 31) { int l = pos - 24; v = P.pn1[gb * PN + ng * 7 + l]; hp = 384 + ng * 7 + l; }
    else if (pos < 35) { int l = pos - 31; v = P.ln1[gb * LN + ng * 4 + l]; hp = 496 + ng * 4 + l; }
    else if (pos < 89) { int l = pos - 35; v = P.kc1[(size_t)gb * KC + ng * 54 + l]; hp = 560 + ng * 54 + l; }
    else               { v = P.mbon[gb * MB + ng]; hp = 1424 + ng; }
    P.h2[(size_t)gb * HID + hp] = v;
  }
}

extern "C" void kernel_launch(void* const* d_in, const int* in_sizes, int n_in,
                              void* d_out, int out_size, void* d_ws, size_t ws_size,
                              hipStream_t stream) {
  Params P;
  P.obs       = (const float*)d_in[0];
  P.h         = (const float*)d_in[1];
  P.in_orn_w  = (const float*)d_in[2];
  P.in_orn_b  = (const float*)d_in[3];
  P.W_oto     = (const float*)d_in[4];
  P.W_lto     = (const float*)d_in[5];
  P.W_otp     = (const float*)d_in[6];
  P.W_ltp     = (const float*)d_in[7];
  P.W_ptp     = (const float*)d_in[8];
  P.W_otl     = (const float*)d_in[9];
  P.W_ptl     = (const float*)d_in[10];
  P.W_ltl     = (const float*)d_in[11];
  P.W_ktk     = (const float*)d_in[12];
  P.W_mtk     = (const float*)d_in[13];
  P.W_ptk     = (const float*)d_in[14];
  P.W_ktm     = (const float*)d_in[15];
  P.b_orn     = (const float*)d_in[16];
  P.b_pn      = (const float*)d_in[17];
  P.b_ln      = (const float*)d_in[18];
  P.b_kc      = (const float*)d_in[19];
  P.b_mbon    = (const float*)d_in[20];
  P.readout_w = (const float*)d_in[21];
  P.readout_b = (const float*)d_in[22];

  float* ws = (float*)d_ws;
  size_t off = 0;
  P.orn0 = ws + off; off += (size_t)Bsz * ORN;
  P.orn1 = ws + off; off += (size_t)Bsz * ORN;
  P.pn0  = ws + off; off += (size_t)Bsz * PN;
  P.pn1  = ws + off; off += (size_t)Bsz * PN;
  P.ln0  = ws + off; off += (size_t)Bsz * LN;
  P.ln1  = ws + off; off += (size_t)Bsz * LN;
  P.kc0  = ws + off; off += (size_t)Bsz * KC;
  P.kc1  = ws + off; off += (size_t)Bsz * KC;
  P.mbon = ws + off; off += (size_t)Bsz * MB;
  P.bar  = (int*)(ws + off); off += 16 * 64;  // 16 batch groups x 64 ints

  P.y  = (float*)d_out;
  P.h2 = (float*)d_out + (size_t)Bsz * Tst * HID;

  void* args[] = { &P };
  hipLaunchCooperativeKernel((void*)conn_kernel, dim3(256), dim3(NTHREADS), args, 0, stream);
}